// Round 4
// baseline (499.374 us; speedup 1.0000x reference)
//
#include <hip/hip_runtime.h>

// BackWarp: dense bilinear backward warp — pipelined-strip version.
// Evidence r0-r3: all structures ~128-137us, VALU<36%, HBM<45%, occ 60-80%.
// XCD batch-affinity swizzle (r3) gave -7% and FETCH 214->144MB (keep it).
// Remaining theory: every thread's serial chain starts with a compulsory
// HBM-stream flow load -> addr -> gather; that first-hop latency is exposed
// in every prior round. Fix: per-block tile loop with flow prefetched one
// iteration ahead (NT), so gathers start immediately each iteration.
// Also: 4px/thread => flow 2x dwordx4, out 3x dwordx4 (16B-aligned, exact
// 172.8MB write stream), VMEM instrs 8 -> 5.25 per px.

#define BW_B 16
#define BW_H 720
#define BW_W 1280
#define BW_C 3

#define NXCD 8
#define PX 4                         // x-pixels per thread
#define STRIP_W (64 * PX)            // 256
#define NSTRIP (BW_W / STRIP_W)      // 5
#define KITER 5                      // row-iterations per block (4 rows each)
#define ROWS_PB (4 * KITER)          // 20 rows per block
#define NYC (BW_H / ROWS_PB)         // 36
#define WG_PER_BATCH (NSTRIP * NYC)  // 180
#define BATCH_PER_XCD (BW_B / NXCD)  // 2
#define WG_PER_XCD (WG_PER_BATCH * BATCH_PER_XCD)  // 360
#define NWG (NXCD * WG_PER_XCD)      // 2880

typedef float f4a __attribute__((ext_vector_type(4)));               // 16B-aligned
typedef float f4u __attribute__((ext_vector_type(4), aligned(4)));
typedef float f2u __attribute__((ext_vector_type(2), aligned(4)));

__device__ __forceinline__ void prep(
    const float* __restrict__ imgb, float fy_flow, float fx_flow,
    int x, int y,
    const float*& p0, const float*& p1, float& ax, float& ay) {
    const float qy = (float)y - fy_flow;
    const float qx = (float)x - fx_flow;
    float fy = fminf(fmaxf(floorf(qy), 0.0f), (float)(BW_H - 2));
    float fx = fminf(fmaxf(floorf(qx), 0.0f), (float)(BW_W - 2));
    ay = fminf(fmaxf(qy - fy, 0.0f), 1.0f);
    ax = fminf(fmaxf(qx - fx, 0.0f), 1.0f);
    p0 = imgb + ((int)fy * BW_W + (int)fx) * BW_C;
    p1 = p0 + BW_W * BW_C;
}

struct Col { float c0, c1, c2; };

__device__ __forceinline__ Col blend(f4u t, f2u t2, f4u bm, f2u b2,
                                     float ax, float ay) {
    const float it0 = t.x + ax * (t.w - t.x);
    const float it1 = t.y + ax * (t2.x - t.y);
    const float it2 = t.z + ax * (t2.y - t.z);
    const float ib0 = bm.x + ax * (bm.w - bm.x);
    const float ib1 = bm.y + ax * (b2.x - bm.y);
    const float ib2 = bm.z + ax * (b2.y - bm.z);
    Col r;
    r.c0 = it0 + ay * (ib0 - it0);
    r.c1 = it1 + ay * (ib1 - it1);
    r.c2 = it2 + ay * (ib2 - it2);
    return r;
}

__global__ __launch_bounds__(256) void backwarp_kernel(
    const float* __restrict__ image,
    const float* __restrict__ flow,
    float* __restrict__ out) {
    // ---- XCD batch-affinity swizzle (r3, proven): XCD k owns batches 2k,2k+1
    const unsigned wg = blockIdx.x;            // 0..2879
    const unsigned xcd = wg & (NXCD - 1);
    const unsigned w = wg >> 3;                // 0..359 within XCD
    const unsigned bl = w / WG_PER_BATCH;      // 0..1
    const unsigned rem = w % WG_PER_BATCH;     // 0..179
    const unsigned yc = rem / NSTRIP;          // 0..35
    const unsigned bx = rem % NSTRIP;          // 0..4
    const unsigned b = xcd * BATCH_PER_XCD + bl;

    const int tx = threadIdx.x;                // 0..63
    const int ty = threadIdx.y;                // 0..3
    const int x = (int)(bx * STRIP_W) + tx * PX;
    int y = (int)(yc * ROWS_PB) + ty;          // this wave's row; +4 per iter

    const float* __restrict__ imgb = image + (size_t)b * (BW_H * BW_W * BW_C);
    const unsigned base_b = b * (BW_H * BW_W);

    const f4a* __restrict__ fl = (const f4a*)flow;   // one f4 = 2 px of flow

    // prologue: flow for first iteration (the only exposed flow latency)
    unsigned fi = (base_b + (unsigned)y * BW_W + (unsigned)x) >> 1;
    f4a fa = __builtin_nontemporal_load(fl + fi);        // px 0,1
    f4a fb = __builtin_nontemporal_load(fl + fi + 1);    // px 2,3

    #pragma unroll 1
    for (int k = 0; k < KITER; ++k) {
        // ---- 1. addresses for 4 px from current flow ----
        const float *p0[PX], *p1[PX];
        float ax[PX], ay[PX];
        prep(imgb, fa.x, fa.y, x + 0, y, p0[0], p1[0], ax[0], ay[0]);
        prep(imgb, fa.z, fa.w, x + 1, y, p0[1], p1[1], ax[1], ay[1]);
        prep(imgb, fb.x, fb.y, x + 2, y, p0[2], p1[2], ax[2], ay[2]);
        prep(imgb, fb.z, fb.w, x + 3, y, p0[3], p1[3], ax[3], ay[3]);

        // ---- 2. issue all 16 corner gathers ----
        f4u t0[PX]; f2u t1[PX]; f4u b0[PX]; f2u b1[PX];
        #pragma unroll
        for (int j = 0; j < PX; ++j) {
            t0[j] = *(const f4u*)p0[j];
            t1[j] = *(const f2u*)(p0[j] + 4);
            b0[j] = *(const f4u*)p1[j];
            b1[j] = *(const f2u*)(p1[j] + 4);
        }

        // ---- 3. prefetch next iteration's flow (NT; newest in vmcnt order,
        //         so blend's counted waits never drain it) ----
        int yn = y + 4;
        yn = yn > (BW_H - 1) ? (BW_H - 1) : yn;       // last-iter clamp (uniform)
        const unsigned fin = (base_b + (unsigned)yn * BW_W + (unsigned)x) >> 1;
        fa = __builtin_nontemporal_load(fl + fin);
        fb = __builtin_nontemporal_load(fl + fin + 1);

        // ---- 4. blend ----
        Col c0 = blend(t0[0], t1[0], b0[0], b1[0], ax[0], ay[0]);
        Col c1 = blend(t0[1], t1[1], b0[1], b1[1], ax[1], ay[1]);
        Col c2 = blend(t0[2], t1[2], b0[2], b1[2], ax[2], ay[2]);
        Col c3 = blend(t0[3], t1[3], b0[3], b1[3], ax[3], ay[3]);

        // ---- 5. three 16B-aligned NT stores (12 contiguous floats) ----
        float* o = out + (size_t)(base_b + (unsigned)y * BW_W + (unsigned)x) * BW_C;
        const f4a s0 = {c0.c0, c0.c1, c0.c2, c1.c0};
        const f4a s1 = {c1.c1, c1.c2, c2.c0, c2.c1};
        const f4a s2 = {c2.c2, c3.c0, c3.c1, c3.c2};
        __builtin_nontemporal_store(s0, (f4a*)o);
        __builtin_nontemporal_store(s1, (f4a*)(o + 4));
        __builtin_nontemporal_store(s2, (f4a*)(o + 8));

        y += 4;
    }
}

extern "C" void kernel_launch(void* const* d_in, const int* in_sizes, int n_in,
                              void* d_out, int out_size, void* d_ws, size_t ws_size,
                              hipStream_t stream) {
    const float* image = (const float*)d_in[0];
    const float* flow  = (const float*)d_in[1];
    float* out = (float*)d_out;

    dim3 block(64, 4, 1);                  // 256 threads
    dim3 grid(NWG, 1, 1);                  // 2880 workgroups, 1D for swizzle
    backwarp_kernel<<<grid, block, 0, stream>>>(image, flow, out);
}

// Round 5
// 374.302 us; speedup vs baseline: 1.3341x; 1.3341x over previous
//
#include <hip/hip_runtime.h>

// BackWarp: dense bilinear backward warp.
// Model after r0-r4: limiter is per-CU vector-memory line-event throughput.
// r0/r1/r3 (different structures, same ~1.5 line-events/px) all ~5.5 cyc/px;
// r4 (2.5 line-events/px from 48B lane strides) = 10.8 cyc/px. VALU/HBM/occ all
// far from ceilings in every round.
// This round: keep r3 exactly (128us: XCD batch-affinity swizzle, 64x8 tile,
// 2px/thread, NT flow dwordx2) and fix the store side: stage the block's 6KB
// output in LDS, then write back as dense lane-contiguous dwordx4 NT stores.
// Store lane-ops 3 -> 0.75 /px; write line-touches 0.56 -> 0.19 /px (1x, aligned).

#define BW_B 16
#define BW_H 720
#define BW_W 1280
#define BW_C 3

#define TILE_W 64
#define TILE_H 8

#define GRID_X (BW_W / TILE_W)   // 20
#define GRID_Y (BW_H / TILE_H)   // 90
#define WG_PER_BATCH (GRID_X * GRID_Y)          // 1800
#define NXCD 8
#define BATCH_PER_XCD (BW_B / NXCD)             // 2
#define WG_PER_XCD (WG_PER_BATCH * BATCH_PER_XCD)  // 3600

// LDS out-tile: 8 rows x 192 floats (768B/row) = 6KB
#define ROW_F (TILE_W * BW_C)            // 192 floats per tile row
#define CHUNKS_PER_ROW (ROW_F / 4)       // 48 dwordx4 chunks
#define NCHUNK (TILE_H * CHUNKS_PER_ROW) // 384

typedef float floatx2 __attribute__((ext_vector_type(2)));
typedef float f4a __attribute__((ext_vector_type(4)));              // 16B-aligned
typedef float f4u __attribute__((ext_vector_type(4), aligned(4)));
typedef float f2u __attribute__((ext_vector_type(2), aligned(4)));

__device__ __forceinline__ void warp_one(
    const float* __restrict__ imgb, floatx2 f, int x, int y,
    float* __restrict__ dst) {            // dst: 3 floats in LDS
    const float qy = (float)y - f.x;
    const float qx = (float)x - f.y;

    float fy = floorf(qy);
    fy = fminf(fmaxf(fy, 0.0f), (float)(BW_H - 2));
    float fx = floorf(qx);
    fx = fminf(fmaxf(fx, 0.0f), (float)(BW_W - 2));
    const float ay = fminf(fmaxf(qy - fy, 0.0f), 1.0f);
    const float ax = fminf(fmaxf(qx - fx, 0.0f), 1.0f);
    const int iy = (int)fy;
    const int ix = (int)fx;

    const float* __restrict__ p0 = imgb + (iy * BW_W + ix) * BW_C;  // top-left
    const float* __restrict__ p1 = p0 + BW_W * BW_C;                // bottom-left

    const f4u t  = *(const f4u*)p0;  const f2u t2 = *(const f2u*)(p0 + 4);
    const f4u bm = *(const f4u*)p1;  const f2u b2 = *(const f2u*)(p1 + 4);

    const float tl0 = t.x,  tl1 = t.y,  tl2 = t.z;
    const float tr0 = t.w,  tr1 = t2.x, tr2 = t2.y;
    const float bl0 = bm.x, bl1 = bm.y, bl2 = bm.z;
    const float br0 = bm.w, br1 = b2.x, br2 = b2.y;

    const float it0 = tl0 + ax * (tr0 - tl0);
    const float it1 = tl1 + ax * (tr1 - tl1);
    const float it2 = tl2 + ax * (tr2 - tl2);
    const float ib0 = bl0 + ax * (br0 - bl0);
    const float ib1 = bl1 + ax * (br1 - bl1);
    const float ib2 = bl2 + ax * (br2 - bl2);

    dst[0] = it0 + ay * (ib0 - it0);
    dst[1] = it1 + ay * (ib1 - it1);
    dst[2] = it2 + ay * (ib2 - it2);
}

__global__ __launch_bounds__(256) void backwarp_kernel(
    const float* __restrict__ image,
    const float* __restrict__ flow,
    float* __restrict__ out) {
    __shared__ float smem[TILE_H * ROW_F];   // 6KB out-tile

    // ---- XCD batch-affinity swizzle (r3, proven -7%): XCD k owns batches 2k,2k+1
    const unsigned wg = blockIdx.x;            // 0..28799
    const unsigned xcd = wg & (NXCD - 1);
    const unsigned w = wg >> 3;                // 0..3599 within XCD
    const unsigned b = xcd * BATCH_PER_XCD + w / WG_PER_BATCH;
    const unsigned rem = w % WG_PER_BATCH;     // 0..1799
    const unsigned by = rem / GRID_X;          // 0..89
    const unsigned bx = rem % GRID_X;          // 0..19

    const int tx = threadIdx.x;                // 0..63
    const int ty = threadIdx.y;                // 0..3
    const int x0 = (int)(bx * TILE_W);
    const int y0t = (int)(by * TILE_H);
    const int x = x0 + tx;
    const int y0 = y0t + ty;                   // rows ty and ty+4
    const int y1 = y0 + 4;

    const float* __restrict__ imgb = image + (size_t)b * (BW_H * BW_W * BW_C);
    const unsigned base_b = b * (BW_H * BW_W);

    const unsigned i0 = base_b + (unsigned)y0 * BW_W + (unsigned)x;
    const unsigned i1 = base_b + (unsigned)y1 * BW_W + (unsigned)x;

    // coalesced 8B NT flow loads (read-once stream)
    const floatx2* __restrict__ fl = (const floatx2*)flow;
    const floatx2 f0 = __builtin_nontemporal_load(fl + i0);
    const floatx2 f1 = __builtin_nontemporal_load(fl + i1);

    // compute both pixels into the LDS out-tile
    // LDS write addr 3*tx words: lanes tx, tx+32 share a bank (2-way = free)
    warp_one(imgb, f0, x, y0, &smem[ty * ROW_F + 3 * tx]);
    warp_one(imgb, f1, x, y1, &smem[(ty + 4) * ROW_F + 3 * tx]);

    __syncthreads();

    // ---- dense coalesced writeback: 384 dwordx4 chunks, NT ----
    const int tid = ty * 64 + tx;              // 0..255
    {
        const int c = tid;                     // chunks 0..255
        const int s = c / CHUNKS_PER_ROW;      // tile row 0..5
        const int col = c - s * CHUNKS_PER_ROW;
        const f4a v = *(const f4a*)&smem[s * ROW_F + col * 4];
        float* o = out + (size_t)(base_b + (unsigned)(y0t + s) * BW_W + (unsigned)x0) * BW_C;
        __builtin_nontemporal_store(v, (f4a*)(o + col * 4));
    }
    if (tid < NCHUNK - 256) {                  // chunks 256..383 (waves 0,1 only)
        const int c = tid + 256;
        const int s = c / CHUNKS_PER_ROW;      // tile row 5..7
        const int col = c - s * CHUNKS_PER_ROW;
        const f4a v = *(const f4a*)&smem[s * ROW_F + col * 4];
        float* o = out + (size_t)(base_b + (unsigned)(y0t + s) * BW_W + (unsigned)x0) * BW_C;
        __builtin_nontemporal_store(v, (f4a*)(o + col * 4));
    }
}

extern "C" void kernel_launch(void* const* d_in, const int* in_sizes, int n_in,
                              void* d_out, int out_size, void* d_ws, size_t ws_size,
                              hipStream_t stream) {
    const float* image = (const float*)d_in[0];
    const float* flow  = (const float*)d_in[1];
    float* out = (float*)d_out;

    dim3 block(TILE_W, TILE_H / 2, 1);          // 64 x 4 = 256
    dim3 grid(NXCD * WG_PER_XCD, 1, 1);         // 28800, 1D for swizzle
    backwarp_kernel<<<grid, block, 0, stream>>>(image, flow, out);
}

// Round 6
// 361.304 us; speedup vs baseline: 1.3821x; 1.0360x over previous
//
#include <hip/hip_runtime.h>

// BackWarp: dense bilinear backward warp — vertical-MLP probe.
// Model after r0-r5: five structures all ~128-137us with every pipe <45% =>
// outstanding-read-slot saturation (throughput = in-flight reads / latency).
// r4 confirms: line-split loads (48B lane stride) doubled slot cost -> 2x time.
// This round: 4 independent px chains per thread stacked VERTICALLY (y+4k),
// lane stride stays 12B (clean), stores stay r3's direct 3-dword NT pattern,
// XCD batch-affinity swizzle kept. All 4 flow loads then all 16 gathers issue
// before any blend -> ~20 reads in flight per wave (2x r3).

#define BW_B 16
#define BW_H 720
#define BW_W 1280
#define BW_C 3

#define TILE_W 64
#define TILE_H 16                 // 4 waves x 4 px each, row stride 4
#define PXY 4                     // vertical pixels per thread

#define GRID_X (BW_W / TILE_W)    // 20
#define GRID_Y (BW_H / TILE_H)    // 45
#define WG_PER_BATCH (GRID_X * GRID_Y)             // 900
#define NXCD 8
#define BATCH_PER_XCD (BW_B / NXCD)                // 2
#define WG_PER_XCD (WG_PER_BATCH * BATCH_PER_XCD)  // 1800
#define NWG (NXCD * WG_PER_XCD)                    // 14400

typedef float floatx2 __attribute__((ext_vector_type(2)));
typedef float f4u __attribute__((ext_vector_type(4), aligned(4)));
typedef float f2u __attribute__((ext_vector_type(2), aligned(4)));

__global__ __launch_bounds__(256) void backwarp_kernel(
    const float* __restrict__ image,
    const float* __restrict__ flow,
    float* __restrict__ out) {
    // ---- XCD batch-affinity swizzle (r3, proven): XCD k owns batches 2k,2k+1
    const unsigned wg = blockIdx.x;            // 0..14399
    const unsigned xcd = wg & (NXCD - 1);
    const unsigned w = wg >> 3;                // 0..1799 within XCD
    const unsigned b = xcd * BATCH_PER_XCD + w / WG_PER_BATCH;
    const unsigned rem = w % WG_PER_BATCH;     // 0..899
    const unsigned by = rem / GRID_X;          // 0..44
    const unsigned bx = rem % GRID_X;          // 0..19

    const int tx = threadIdx.x;                // 0..63
    const int ty = threadIdx.y;                // 0..3
    const int x = (int)(bx * TILE_W) + tx;
    const int yb = (int)(by * TILE_H) + ty;    // px rows: yb + 4k, k=0..3

    const float* __restrict__ imgb = image + (size_t)b * (BW_H * BW_W * BW_C);
    const unsigned base_b = b * (BW_H * BW_W);

    // ---- 1. issue all 4 flow loads (independent, NT read-once stream) ----
    const floatx2* __restrict__ fl = (const floatx2*)flow;
    unsigned idx[PXY];
    floatx2 f[PXY];
    #pragma unroll
    for (int k = 0; k < PXY; ++k) {
        idx[k] = base_b + (unsigned)(yb + 4 * k) * BW_W + (unsigned)x;
        f[k] = __builtin_nontemporal_load(fl + idx[k]);
    }

    // ---- 2. prep + issue all 16 gathers (deep counted-vmcnt pipeline) ----
    f4u t0[PXY]; f2u t1[PXY]; f4u b0[PXY]; f2u b1[PXY];
    float axv[PXY], ayv[PXY];
    #pragma unroll
    for (int k = 0; k < PXY; ++k) {
        const int y = yb + 4 * k;
        const float qy = (float)y - f[k].x;
        const float qx = (float)x - f[k].y;
        float fy = fminf(fmaxf(floorf(qy), 0.0f), (float)(BW_H - 2));
        float fx = fminf(fmaxf(floorf(qx), 0.0f), (float)(BW_W - 2));
        ayv[k] = fminf(fmaxf(qy - fy, 0.0f), 1.0f);
        axv[k] = fminf(fmaxf(qx - fx, 0.0f), 1.0f);
        // 32-bit offset + uniform base -> saddr-form loads (fewer addr VGPRs)
        const unsigned o0 = ((unsigned)(int)fy * BW_W + (unsigned)(int)fx) * BW_C;
        const float* __restrict__ p0 = imgb + o0;            // top-left
        const float* __restrict__ p1 = p0 + BW_W * BW_C;     // bottom-left
        t0[k] = *(const f4u*)p0;  t1[k] = *(const f2u*)(p0 + 4);
        b0[k] = *(const f4u*)p1;  b1[k] = *(const f2u*)(p1 + 4);
    }

    // ---- 3. blend + store (r3's proven 3-dword NT store pattern) ----
    #pragma unroll
    for (int k = 0; k < PXY; ++k) {
        const float ax = axv[k], ay = ayv[k];
        const float it0 = t0[k].x + ax * (t0[k].w - t0[k].x);
        const float it1 = t0[k].y + ax * (t1[k].x - t0[k].y);
        const float it2 = t0[k].z + ax * (t1[k].y - t0[k].z);
        const float ib0 = b0[k].x + ax * (b0[k].w - b0[k].x);
        const float ib1 = b0[k].y + ax * (b1[k].x - b0[k].y);
        const float ib2 = b0[k].z + ax * (b1[k].y - b0[k].z);

        float* o = out + (size_t)idx[k] * BW_C;
        __builtin_nontemporal_store(it0 + ay * (ib0 - it0), o + 0);
        __builtin_nontemporal_store(it1 + ay * (ib1 - it1), o + 1);
        __builtin_nontemporal_store(it2 + ay * (ib2 - it2), o + 2);
    }
}

extern "C" void kernel_launch(void* const* d_in, const int* in_sizes, int n_in,
                              void* d_out, int out_size, void* d_ws, size_t ws_size,
                              hipStream_t stream) {
    const float* image = (const float*)d_in[0];
    const float* flow  = (const float*)d_in[1];
    float* out = (float*)d_out;

    dim3 block(TILE_W, 4, 1);              // 64 x 4 = 256
    dim3 grid(NWG, 1, 1);                  // 14400, 1D for swizzle
    backwarp_kernel<<<grid, block, 0, stream>>>(image, flow, out);
}